// Round 1
// 1075.309 us; speedup vs baseline: 1.1897x; 1.1897x over previous
//
#include <hip/hip_runtime.h>
#include <stdint.h>
#include <stddef.h>

typedef unsigned short u16;
typedef __attribute__((ext_vector_type(8))) short short8;    // 8 bf16 input frag (4 VGPRs)
typedef __attribute__((ext_vector_type(8))) unsigned short ushort8;
typedef __attribute__((ext_vector_type(4))) float f32x4;     // MFMA 16x16 accum

#define NTOK 64
#define QKVC 1536
#define DIM  512
#define QK_REGION 4608   // per-wave u16: q[0:2048], k[2304:4352]; P[64][72] overwrites [0:4608]

__device__ __forceinline__ float bf2f(u16 u) {
  union { unsigned int i; float f; } x; x.i = ((unsigned int)u) << 16; return x.f;
}
__device__ __forceinline__ u16 f2bf(float f) {
  union { float f; unsigned int i; } x; x.f = f;
  unsigned int u = x.i;
  u += 0x7fffu + ((u >> 16) & 1u);   // RNE
  return (u16)(u >> 16);
}

// async global->LDS, 16B per lane; LDS dest = wave-uniform base + lane*16
__device__ __forceinline__ void async16(const void* g, void* l) {
  __builtin_amdgcn_global_load_lds((const __attribute__((address_space(1))) void*)g,
                                   (__attribute__((address_space(3))) void*)l,
                                   16, 0, 0);
}

template<int L>
__device__ __forceinline__ void wait_vm() {
  if constexpr (L == 4)      asm volatile("s_waitcnt vmcnt(4)" ::: "memory");
  else if constexpr (L == 3) asm volatile("s_waitcnt vmcnt(3)" ::: "memory");
  else                       asm volatile("s_waitcnt vmcnt(0)" ::: "memory");
}

__device__ __forceinline__ f32x4 shfl_xor4(f32x4 v, int m) {
  f32x4 r;
  #pragma unroll
  for (int e = 0; e < 4; ++e) r[e] = __shfl_xor(v[e], m, 64);
  return r;
}
__device__ __forceinline__ f32x4 max44(f32x4 a, f32x4 b) {
  f32x4 r;
  #pragma unroll
  for (int e = 0; e < 4; ++e) r[e] = fmaxf(a[e], b[e]);
  return r;
}

// ---------------- dtype detection ----------------
__global__ void detect_k(const u16* __restrict__ w_raw, int* __restrict__ flag) {
  if (threadIdx.x == 0 && blockIdx.x == 0) {
    int cnt = 0;
    for (int i = 0; i < 512; ++i) {
      float v = bf2f(w_raw[i]);
      if (!(v <= 0.5f && v >= -0.5f)) ++cnt;   // counts NaN too
    }
    flag[0] = (cnt > 16) ? 1 : 0;              // 1 = inputs are fp32
  }
}

// ---------------- prep kernels ----------------

// vectorized canonical bf16 copy: 8 elems/thread (n must be divisible by 8)
__global__ void cvt8_k(const float* __restrict__ fsrc, const u16* __restrict__ usrc,
                       u16* __restrict__ dst, int n, const int* __restrict__ flag) {
  int i = (blockIdx.x * 256 + threadIdx.x) * 8;
  if (i >= n) return;
  if (flag[0]) {
    f32x4 a = *(const f32x4*)(fsrc + i);
    f32x4 b = *(const f32x4*)(fsrc + i + 4);
    ushort8 o;
    #pragma unroll
    for (int e = 0; e < 4; ++e) { o[e] = f2bf(a[e]); o[e + 4] = f2bf(b[e]); }
    *(ushort8*)(dst + i) = o;
  } else {
    *(ushort8*)(dst + i) = *(const ushort8*)(usrc + i);
  }
}

// dst[n*R+k] = (bf16) src[k*C+n]  (transpose to N x K)  -- one-time, tiny
__global__ void transpose_k(const float* __restrict__ fsrc, const u16* __restrict__ usrc,
                            u16* __restrict__ dst, int R, int C, const int* __restrict__ flag) {
  int idx = blockIdx.x * 256 + threadIdx.x;
  int n = idx / R, k = idx % R;
  if (flag[0]) dst[idx] = f2bf(fsrc[k * C + n]);
  else         dst[idx] = usrc[k * C + n];
}

__global__ void bias_expand_k(const float* __restrict__ ftab, const u16* __restrict__ utab,
                              float* __restrict__ biasc, const int* __restrict__ flag) {
  int t = blockIdx.x * 256 + threadIdx.x;   // 65536 total
  int r    = t & 3;
  int lane = (t >> 2) & 63;
  int ni   = (t >> 8) & 3;
  int mi   = (t >> 10) & 3;
  int h    = t >> 12;
  int n = mi * 16 + (lane >> 4) * 4 + r;
  int m = ni * 16 + (lane & 15);
  int i1 = n >> 3, j1 = n & 7, i2 = m >> 3, j2 = m & 7;
  int off = h * 225 + (i1 - i2 + 7) * 15 + (j1 - j2 + 7);
  if (flag[0]) biasc[t] = ftab[off];
  else         biasc[t] = bf2f(utab[off]);
}

// ---------------- legacy 128x128 GEMM (fallback for odd chunk sizes) ----------------
__global__ __launch_bounds__(256) void gemm_bt(
    const u16* __restrict__ A, const u16* __restrict__ Bt, const u16* __restrict__ bias,
    u16* __restrict__ Cu, float* __restrict__ Cf, const int* __restrict__ outf32,
    int N, int K)
{
  __shared__ __attribute__((aligned(16))) u16 Al[128 * 32];
  __shared__ __attribute__((aligned(16))) u16 Bl[128 * 32];

  const int tn = blockIdx.x * 128;
  const int tm = blockIdx.y * 128;
  const int lane = threadIdx.x & 63;
  const int wave = threadIdx.x >> 6;
  const int lr = lane & 15, quad = lane >> 4;
  const int wm = (wave & 1) * 64, wn = (wave >> 1) * 64;

  const f32x4 zero4 = {0.f, 0.f, 0.f, 0.f};
  f32x4 acc[4][4];
  #pragma unroll
  for (int mi = 0; mi < 4; ++mi)
    #pragma unroll
    for (int ni = 0; ni < 4; ++ni) acc[mi][ni] = zero4;

  for (int k0 = 0; k0 < K; k0 += 32) {
    #pragma unroll
    for (int i = 0; i < 2; ++i) {
      int c = (i * 4 + wave) * 64 + lane;
      int row = c >> 2, off = (c & 3) << 3;
      async16(A  + (size_t)(tm + row) * K + k0 + off, Al + (i * 4 + wave) * 512);
      async16(Bt + (size_t)(tn + row) * K + k0 + off, Bl + (i * 4 + wave) * 512);
    }
    __syncthreads();

    short8 af[4], bfr[4];
    #pragma unroll
    for (int mi = 0; mi < 4; ++mi)
      af[mi] = *(const short8*)&Al[(wm + mi * 16 + lr) * 32 + quad * 8];
    #pragma unroll
    for (int ni = 0; ni < 4; ++ni)
      bfr[ni] = *(const short8*)&Bl[(wn + ni * 16 + lr) * 32 + quad * 8];

    #pragma unroll
    for (int mi = 0; mi < 4; ++mi)
      #pragma unroll
      for (int ni = 0; ni < 4; ++ni)
        acc[mi][ni] = __builtin_amdgcn_mfma_f32_16x16x32_bf16(af[mi], bfr[ni], acc[mi][ni], 0, 0, 0);
    __syncthreads();
  }

  const int f32o = outf32 ? outf32[0] : 0;
  #pragma unroll
  for (int ni = 0; ni < 4; ++ni) {
    int col = tn + wn + ni * 16 + lr;
    float bv = bf2f(bias[col]);
    #pragma unroll
    for (int mi = 0; mi < 4; ++mi) {
      size_t rb = (size_t)(tm + wm + mi * 16 + quad * 4);
      #pragma unroll
      for (int r = 0; r < 4; ++r) {
        float val = acc[mi][ni][r] + bv;
        size_t ofs = (rb + r) * (size_t)N + col;
        if (f32o) Cf[ofs] = val;
        else      Cu[ofs] = f2bf(val);
      }
    }
  }
}

// ---------------- pipelined GEMM: C[M][N] = A[M][K] @ Bt[N][K]^T + bias[N] ----------
// BMxBN tile, BK=32, 8 waves (512 thr), per-wave (BM/WR)x(BN/WC) output.
// 3 LDS buffers, 2-tiles-ahead prefetch via global_load_lds, counted vmcnt (never
// drained in steady state), one raw s_barrier per K-tile, setprio around MFMA.
// Linear [rows][32] LDS layout is at the ds_read_b128 bank floor (row stride 64B
// spreads a wave over all 32 banks) -> no swizzle needed, gload_lds stays linear.
template<int BM, int BN, int WR, int WC>
__global__ __launch_bounds__(512, 2) void gemm_bt_p(
    const u16* __restrict__ A, const u16* __restrict__ Bt, const u16* __restrict__ bias,
    u16* __restrict__ Cu, float* __restrict__ Cf, const int* __restrict__ outf32,
    int N, int K)
{
  constexpr int BK = 32;
  constexpr int LA = BM / 128, LB = BN / 128, L = LA + LB;  // gloads/thread/tile
  constexpr int MI = BM / (WR * 16), NI = BN / (WC * 16);

  __shared__ __attribute__((aligned(16))) u16 Al[3][BM * BK];
  __shared__ __attribute__((aligned(16))) u16 Bl[3][BN * BK];

  const int tn = blockIdx.x * BN;
  const int tm = blockIdx.y * BM;
  const int lane = threadIdx.x & 63;
  const int wave = threadIdx.x >> 6;          // 0..7
  const int lr = lane & 15, quad = lane >> 4;
  const int wr = wave / WC, wc = wave % WC;

  // staging map: load ld covers rows [ld*128, ld*128+128)
  // lane -> row = ld*128 + wave*16 + lane/4, elem-off (lane&3)*8  (16B per lane)
  const int srow = wave * 16 + (lane >> 2);
  const int soff = (lane & 3) << 3;
  const u16* ag = A  + (size_t)(tm + srow) * K + soff;
  const u16* bg = Bt + (size_t)(tn + srow) * K + soff;

  const f32x4 zero4 = {0.f, 0.f, 0.f, 0.f};
  f32x4 acc[MI][NI];
  #pragma unroll
  for (int mi = 0; mi < MI; ++mi)
    #pragma unroll
    for (int ni = 0; ni < NI; ++ni) acc[mi][ni] = zero4;

  auto stage = [&](int t) {
    const int buf = ((unsigned)t) % 3u;
    #pragma unroll
    for (int ld = 0; ld < LA; ++ld)
      async16(ag + (size_t)(ld * 128) * K + t * BK, &Al[buf][ld * 4096 + wave * 512]);
    #pragma unroll
    for (int ld = 0; ld < LB; ++ld)
      async16(bg + (size_t)(ld * 128) * K + t * BK, &Bl[buf][ld * 4096 + wave * 512]);
  };

  const int NT = K / BK;     // >= 2 for all uses here (K=512 -> 16)
  stage(0);
  stage(1);

  for (int t = 0; t < NT; ++t) {
    // retire tile t's loads (keep the newest tile's L loads in flight), then sync.
    if (t < NT - 2) wait_vm<L>();
    else            wait_vm<0>();
    __builtin_amdgcn_s_barrier();
    asm volatile("" ::: "memory");   // pin LDS reads / gload issues after the barrier

    const int buf = ((unsigned)t) % 3u;
    short8 af[MI], bfv[NI];
    #pragma unroll
    for (int mi = 0; mi < MI; ++mi)
      af[mi] = *(const short8*)&Al[buf][(wr * (BM / WR) + mi * 16 + lr) * 32 + quad * 8];
    #pragma unroll
    for (int ni = 0; ni < NI; ++ni)
      bfv[ni] = *(const short8*)&Bl[buf][(wc * (BN / WC) + ni * 16 + lr) * 32 + quad * 8];

    if (t + 2 < NT) stage(t + 2);    // into buf (t+2)%3: its last readers (tile t-1)
                                     // finished before the barrier above

    __builtin_amdgcn_s_setprio(1);
    #pragma unroll
    for (int mi = 0; mi < MI; ++mi)
      #pragma unroll
      for (int ni = 0; ni < NI; ++ni)
        acc[mi][ni] = __builtin_amdgcn_mfma_f32_16x16x32_bf16(af[mi], bfv[ni], acc[mi][ni], 0, 0, 0);
    __builtin_amdgcn_s_setprio(0);
  }

  // epilogue: C-layout col = lane&15, row = quad*4 + r (same mapping as legacy kernel)
  const int f32o = outf32 ? outf32[0] : 0;
  #pragma unroll
  for (int ni = 0; ni < NI; ++ni) {
    int col = tn + wc * (BN / WC) + ni * 16 + lr;
    float bv = bf2f(bias[col]);
    #pragma unroll
    for (int mi = 0; mi < MI; ++mi) {
      size_t rb = (size_t)(tm + wr * (BM / WR) + mi * 16 + quad * 4);
      #pragma unroll
      for (int r = 0; r < 4; ++r) {
        float val = acc[mi][ni][r] + bv;
        size_t ofs = (rb + r) * (size_t)N + col;
        if (f32o) Cf[ofs] = val;
        else      Cu[ofs] = f2bf(val);
      }
    }
  }
}

// ---------------- fused window attention: one wave per (window,head) ----------------
__global__ __launch_bounds__(256) void attn_k(
    const u16* __restrict__ qkv,      // [win*64][1536] chunk
    const float* __restrict__ biasc,  // [16][4][4][64][4] C-layout expanded bias
    u16* __restrict__ out)            // [win*64][512] chunk
{
  __shared__ __attribute__((aligned(16))) u16 qkP[4][QK_REGION];
  __shared__ __attribute__((aligned(16))) u16 vTs[4][32 * 72];  // per wave: v^T [d][token], stride 72

  const int lane = threadIdx.x & 63;
  const int wave = threadIdx.x >> 6;
  const int idx = blockIdx.x * 4 + wave;   // (b,h) within chunk
  const int b = idx >> 4, h = idx & 15;
  const int lr = lane & 15, quad = lane >> 4;

  u16* ql = qkP[wave];
  u16* kl = qkP[wave] + 2304;
  u16* Pl = qkP[wave];                     // P[64][72], overwrites dead q/k
  u16* vt = vTs[wave];

  const u16* qg = qkv + (size_t)b * NTOK * QKVC + h * 32;
  const u16* kg = qg + 512;
  const u16* vg = qg + 1024;

  #pragma unroll
  for (int i = 0; i < 4; ++i) {
    int c = i * 64 + lane;
    int row = c >> 2, off = (c & 3) << 3;
    async16(qg + (size_t)row * QKVC + off, ql + i * 512);
    async16(kg + (size_t)row * QKVC + off, kl + i * 512);
  }
  {
    const u16* vrow = vg + (size_t)lane * QKVC;   // token = lane
    #pragma unroll
    for (int c2 = 0; c2 < 4; ++c2) {
      ushort8 vv = *(const ushort8*)(vrow + c2 * 8);
      #pragma unroll
      for (int e = 0; e < 8; ++e)
        vt[(c2 * 8 + e) * 72 + lane] = vv[e];
    }
  }
  __syncthreads();

  const f32x4 zero4 = {0.f, 0.f, 0.f, 0.f};
  f32x4 s[4][4];
  {
    short8 af[4], bfr[4];
    #pragma unroll
    for (int mi = 0; mi < 4; ++mi)
      af[mi] = *(const short8*)&ql[(mi * 16 + lr) * 32 + quad * 8];
    #pragma unroll
    for (int ni = 0; ni < 4; ++ni)
      bfr[ni] = *(const short8*)&kl[(ni * 16 + lr) * 32 + quad * 8];
    #pragma unroll
    for (int mi = 0; mi < 4; ++mi)
      #pragma unroll
      for (int ni = 0; ni < 4; ++ni)
        s[mi][ni] = __builtin_amdgcn_mfma_f32_16x16x32_bf16(af[mi], bfr[ni], zero4, 0, 0, 0);
  }

  const float SCALE = 0.17677669529663687f;   // 32^-0.5
  const float L2E = 1.44269504088896f;
  #pragma unroll
  for (int mi = 0; mi < 4; ++mi)
    #pragma unroll
    for (int ni = 0; ni < 4; ++ni) {
      f32x4 bb = *(const f32x4*)&biasc[((((h * 4 + mi) * 4 + ni) * 64) + lane) * 4];
      s[mi][ni] = s[mi][ni] * SCALE + bb;
    }

  f32x4 mx[4];
  #pragma unroll
  for (int mi = 0; mi < 4; ++mi) {
    mx[mi] = max44(max44(s[mi][0], s[mi][1]), max44(s[mi][2], s[mi][3]));
    #pragma unroll
    for (int m = 1; m <= 8; m <<= 1) mx[mi] = max44(mx[mi], shfl_xor4(mx[mi], m));
  }
  f32x4 sum[4];
  #pragma unroll
  for (int mi = 0; mi < 4; ++mi) {
    #pragma unroll
    for (int ni = 0; ni < 4; ++ni)
      #pragma unroll
      for (int e = 0; e < 4; ++e)
        s[mi][ni][e] = exp2f((s[mi][ni][e] - mx[mi][e]) * L2E);
    sum[mi] = s[mi][0] + s[mi][1] + s[mi][2] + s[mi][3];
    #pragma unroll
    for (int m = 1; m <= 8; m <<= 1) sum[mi] = sum[mi] + shfl_xor4(sum[mi], m);
  }

  #pragma unroll
  for (int mi = 0; mi < 4; ++mi)
    #pragma unroll
    for (int ni = 0; ni < 4; ++ni)
      #pragma unroll
      for (int r = 0; r < 4; ++r) {
        int n = mi * 16 + quad * 4 + r;
        int col = ni * 16 + lr;
        Pl[n * 72 + col] = f2bf(s[mi][ni][r]);
      }
  __syncthreads();

  f32x4 o[4][2];
  #pragma unroll
  for (int mi = 0; mi < 4; ++mi) { o[mi][0] = zero4; o[mi][1] = zero4; }
  #pragma unroll
  for (int ks = 0; ks < 2; ++ks) {
    short8 pf[4], vf[2];
    #pragma unroll
    for (int mi = 0; mi < 4; ++mi)
      pf[mi] = *(const short8*)&Pl[(mi * 16 + lr) * 72 + ks * 32 + quad * 8];
    #pragma unroll
    for (int ni = 0; ni < 2; ++ni)
      vf[ni] = *(const short8*)&vt[(ni * 16 + lr) * 72 + ks * 32 + quad * 8];
    #pragma unroll
    for (int mi = 0; mi < 4; ++mi)
      #pragma unroll
      for (int ni = 0; ni < 2; ++ni)
        o[mi][ni] = __builtin_amdgcn_mfma_f32_16x16x32_bf16(pf[mi], vf[ni], o[mi][ni], 0, 0, 0);
  }

  f32x4 rs[4];
  #pragma unroll
  for (int mi = 0; mi < 4; ++mi)
    #pragma unroll
    for (int e = 0; e < 4; ++e) rs[mi][e] = __builtin_amdgcn_rcpf(sum[mi][e]);

  #pragma unroll
  for (int mi = 0; mi < 4; ++mi)
    #pragma unroll
    for (int ni = 0; ni < 2; ++ni)
      #pragma unroll
      for (int r = 0; r < 4; ++r) {
        int n = mi * 16 + quad * 4 + r;
        int d = ni * 16 + lr;
        out[(size_t)(b * NTOK + n) * DIM + h * 32 + d] = f2bf(o[mi][ni][r] * rs[mi][r]);
      }
}

// ---------------- launch ----------------

extern "C" void kernel_launch(void* const* d_in, const int* in_sizes, int n_in,
                              void* d_out, int out_size, void* d_ws, size_t ws_size,
                              hipStream_t stream)
{
  (void)in_sizes; (void)n_in; (void)out_size;

  const void* x      = d_in[0];   // [2048*64][512]
  const void* w_qkv  = d_in[1];   // [512][1536]
  const void* b_qkv  = d_in[2];   // [1536]
  const void* table  = d_in[3];   // [16][15][15]
  const void* w_proj = d_in[4];   // [512][512]
  const void* b_proj = d_in[5];   // [512]

  char* ws = (char*)d_ws;
  size_t off = 0;
  auto alloc = [&](size_t bytes) -> char* {
    char* p = ws + off; off += (bytes + 255) & ~(size_t)255; return p;
  };
  u16*   wqkvT  = (u16*)alloc(1572864);
  u16*   wprojT = (u16*)alloc(524288);
  float* biasc  = (float*)alloc(262144);
  u16*   bqc    = (u16*)alloc(3072);
  u16*   bpc    = (u16*)alloc(1024);
  int*   flag   = (int*)alloc(256);
  size_t fixed  = off;

  int win = 512;                         // windows per chunk
  while (win > 2 && fixed + (size_t)win * 327680 > ws_size) win >>= 1;
  const int mc = win * 64;               // rows per chunk
  u16* xbfC  = (u16*)alloc((size_t)mc * 512 * 2);
  u16* qkvC  = (u16*)alloc((size_t)mc * 1536 * 2);
  u16* aoutC = (u16*)alloc((size_t)mc * 512 * 2);

  detect_k<<<dim3(1), dim3(64), 0, stream>>>((const u16*)w_qkv, flag);
  transpose_k<<<dim3(3072), dim3(256), 0, stream>>>((const float*)w_qkv, (const u16*)w_qkv, wqkvT, 512, 1536, flag);
  transpose_k<<<dim3(1024), dim3(256), 0, stream>>>((const float*)w_proj, (const u16*)w_proj, wprojT, 512, 512, flag);
  bias_expand_k<<<dim3(256), dim3(256), 0, stream>>>((const float*)table, (const u16*)table, biasc, flag);
  cvt8_k<<<dim3(1), dim3(256), 0, stream>>>((const float*)b_qkv, (const u16*)b_qkv, bqc, 1536, flag);
  cvt8_k<<<dim3(1), dim3(256), 0, stream>>>((const float*)b_proj, (const u16*)b_proj, bpc, 512, flag);

  const int nchunk = 2048 / win;
  for (int c = 0; c < nchunk; ++c) {
    size_t base = (size_t)c * mc * 512;   // element offset into x / out

    cvt8_k<<<dim3((mc * 512) / 2048), dim3(256), 0, stream>>>(
        (const float*)x + base, (const u16*)x + base, xbfC, mc * 512, flag);

    if ((mc & 255) == 0) {
      // qkv = x @ w_qkv + b_qkv   (M=mc, N=1536, K=512), bf16 out
      gemm_bt_p<256, 256, 2, 4><<<dim3(6, mc / 256), dim3(512), 0, stream>>>(
          xbfC, wqkvT, bqc, qkvC, (float*)nullptr, (const int*)nullptr, 1536, 512);

      attn_k<<<dim3(win * 4), dim3(256), 0, stream>>>(qkvC, biasc, aoutC);

      // out = aout @ w_proj + b_proj   (M=mc, N=512, K=512), dtype per flag
      gemm_bt_p<256, 128, 4, 2><<<dim3(4, mc / 256), dim3(512), 0, stream>>>(
          aoutC, wprojT, bpc, (u16*)d_out + base, (float*)d_out + base, flag, 512, 512);
    } else {
      gemm_bt<<<dim3(12, mc / 128), dim3(256), 0, stream>>>(
          xbfC, wqkvT, bqc, qkvC, (float*)nullptr, (const int*)nullptr, 1536, 512);

      attn_k<<<dim3(win * 4), dim3(256), 0, stream>>>(qkvC, biasc, aoutC);

      gemm_bt<<<dim3(4, mc / 128), dim3(256), 0, stream>>>(
          aoutC, wprojT, bpc, (u16*)d_out + base, (float*)d_out + base, flag, 512, 512);
    }
  }
}